// Round 7
// baseline (263.095 us; speedup 1.0000x reference)
//
#include <hip/hip_runtime.h>
#include <hip/hip_bf16.h>

// Difference3DCostVolume: cost[b,c,d,h,w] = l[b,c,h,w] - r[b,c,h,w-d] (w>=d), else 1.0
// Shapes: B=4, C=32, H=96, W=312, D=48. Output [B,C,D,H,W] f32 = 736 MB -> write-bound.
//
// R7: mimic the 6.8 TB/s fill kernel's macro pattern: ALL threads collaboratively
// sweep the output in flat order. Front = 64 (h,w)-slices = 479232 threads
// (1872 blocks x 256, all resident); each thread does exactly 96 iterations at
// stride 64*7488 float4. Per-thread (h,w4) are FIXED; (bc,d) advance by a static
// carry rule -> zero division, all addressing is running adds.
//  - stores: same sliding-window pattern as the fill (the proven 6.8 TB/s shape).
//  - reads: instantaneous input working set ~2 bc-slices (~470 KB) -> L2-hits;
//    HBM input fetch ~31 MB once. No LDS at all.
//  - r vector load at float offset 4*l4-d (4B-aligned). Underflow only possible
//    at k==0 for (bc==0, h==0, w4<12) threads -> peeled iteration with per-lane guard.

#define BB 4
#define CC 32
#define HH 96
#define WW 312
#define DD 48
#define W4 78                      // float4 per row
#define SLICE4 (HH * W4)           // 7488 float4 per (h,w) slice
#define FRONT 64                   // slices per sweep step
#define NT 256
#define NBLOCKS (FRONT * SLICE4 / NT)   // 1872
#define NITER (BB * CC * DD / FRONT)    // 96
#define O4STEP (FRONT * SLICE4)         // 479232
#define DSTEP (FRONT % DD)              // 16

typedef float float4u __attribute__((ext_vector_type(4), aligned(4)));
typedef float float4a __attribute__((ext_vector_type(4)));

__global__ __launch_bounds__(NT) void cost_volume_kernel(
    const float* __restrict__ l, const float* __restrict__ r,
    float* __restrict__ out) {
    const int gtid = blockIdx.x * NT + threadIdx.x;   // 0 .. 479231
    const int sl0 = gtid / SLICE4;                    // 0..63   (one-time div)
    const int s = gtid - sl0 * SLICE4;                // in-slice float4 index
    const int h = s / W4;                             // fixed per thread
    const int w4 = s - h * W4;                        // fixed per thread
    const int w = 4 * w4;                             // fixed per thread

    int bc = sl0 / DD;                                // 0 or 1
    int d = sl0 - bc * DD;

    unsigned o4 = (unsigned)gtid;                     // output float4 index
    unsigned l4 = (unsigned)(bc * SLICE4 + h * W4 + w4); // input float4 index

    // Only threads with bc==0 (sl0<48), h==0, w4<12 can underflow r, only at k==0.
    const bool edgeT = (sl0 < DD) && (h == 0) && (w4 < 12);

    // ---- k = 0, peeled (guarded r path for edge threads)
    {
        const float4a a = *reinterpret_cast<const float4a*>(l + 4 * (size_t)l4);
        float4a b;
        if (edgeT) {
            #pragma unroll
            for (int j = 0; j < 4; ++j) {
                const int off = (int)(4 * l4) + j - d;
                b[j] = (off >= 0) ? r[off] : 0.0f;
            }
        } else {
            b = *reinterpret_cast<const float4u*>(r + (int)(4 * l4) - d);
        }
        float4a v;
        v.x = (w     >= d) ? (a.x - b.x) : 1.0f;
        v.y = (w + 1 >= d) ? (a.y - b.y) : 1.0f;
        v.z = (w + 2 >= d) ? (a.z - b.z) : 1.0f;
        v.w = (w + 3 >= d) ? (a.w - b.w) : 1.0f;
        *reinterpret_cast<float4a*>(out + 4 * (size_t)o4) = v;
    }

    // ---- k = 1..95: pure streaming sweep; r offset strictly positive.
    #pragma unroll 4
    for (int k = 1; k < NITER; ++k) {
        o4 += O4STEP;
        l4 += SLICE4;
        d += DSTEP;
        if (d >= DD) { d -= DD; l4 += SLICE4; }      // bc carry

        const float4a a = *reinterpret_cast<const float4a*>(l + 4 * (size_t)l4);
        const float4u b = *reinterpret_cast<const float4u*>(r + (int)(4 * l4) - d);
        float4a v;
        v.x = (w     >= d) ? (a.x - b.x) : 1.0f;
        v.y = (w + 1 >= d) ? (a.y - b.y) : 1.0f;
        v.z = (w + 2 >= d) ? (a.z - b.z) : 1.0f;
        v.w = (w + 3 >= d) ? (a.w - b.w) : 1.0f;
        *reinterpret_cast<float4a*>(out + 4 * (size_t)o4) = v;
    }
}

extern "C" void kernel_launch(void* const* d_in, const int* in_sizes, int n_in,
                              void* d_out, int out_size, void* d_ws, size_t ws_size,
                              hipStream_t stream) {
    const float* l = (const float*)d_in[0];
    const float* r = (const float*)d_in[1];
    float* out = (float*)d_out;
    cost_volume_kernel<<<dim3(NBLOCKS), dim3(NT), 0, stream>>>(l, r, out);
}

// Round 9
// 150.788 us; speedup vs baseline: 1.7448x; 1.7448x over previous
//
#include <hip/hip_runtime.h>
#include <hip/hip_bf16.h>

// Difference3DCostVolume: cost[b,c,d,h,w] = l[b,c,h,w] - r[b,c,h,w-d] (w>=d), else 1.0
// Shapes: B=4, C=32, H=96, W=312, D=48. Output [B,C,D,H,W] f32 = 736 MB -> write-bound.
//
// R9 = R8 with the W4STEP precedence bug fixed (was (NT/4)%78 = 50; correct is
// NT%78 = 44, the m4 step per inner iteration is NT float4s).
//
// Design: block = (bc, h-quarter of 24 rows), 512 blocks x 512 thr, LDS 60KB -> 2/CU.
//  - stage l,r rows ONCE as straight aligned float4 copies (31 MB total global reads).
//  - d-shift at LDS-read: two aligned ds_read_b128 (lo,hi) + literal word-select,
//    specialized over RR = d&3.
//  - emit all 48 d's per block: each extent = 24 rows = 29952 B contiguous.
//  - pad predicate from running w4 = m4 % 78 (step 44).

#define BB 4
#define CC 32
#define HH 96
#define WW 312
#define DD 48
#define CH 24                  // rows per block
#define NQ (HH / CH)           // 4
#define CHF (CH * WW)          // 7488 floats per chunk
#define CH4 (CHF / 4)          // 1872 float4 per chunk
#define NT 512
#define NBLOCKS (BB * CC * NQ) // 512
#define PAD4 16                // front pad (float4) for rs underflow reads
#define W4STEP (NT % 78)       // 44   (m4 advances by NT=512 per iter; 512 mod 78 = 44)

typedef float float4a __attribute__((ext_vector_type(4)));

__global__ __launch_bounds__(NT) void cost_volume_kernel(
    const float* __restrict__ l, const float* __restrict__ r,
    float* __restrict__ out) {
    const int blk = blockIdx.x;
    const int qtr = blk & 3;
    const int bc = blk >> 2;
    const int h0 = qtr * CH;
    const int tid = threadIdx.x;

    __shared__ float ls[CHF];                 // 29952 B
    __shared__ float rsm[PAD4 * 4 + CHF];     // 30208 B (front pad + data)

    float4a* ls4 = reinterpret_cast<float4a*>(ls);
    float4a* rs4 = reinterpret_cast<float4a*>(rsm);   // data at rs4[PAD4 + i]

    // ---- stage: straight contiguous copies (24 full rows each), all vec4.
    {
        const float4a* lsrc = reinterpret_cast<const float4a*>(
            l + ((size_t)bc * HH + h0) * WW);
        const float4a* rsrc = reinterpret_cast<const float4a*>(
            r + ((size_t)bc * HH + h0) * WW);
        for (int i = tid; i < CH4; i += NT) {
            ls4[i] = lsrc[i];
            rs4[PAD4 + i] = rsrc[i];
        }
    }
    __syncthreads();

    const int w40 = tid % 78;                 // w4 of this thread's first item
    float* obase = out + ((size_t)bc * DD * HH + h0) * (size_t)WW;

    // For d = 4*dq + RR: r window per lane j is chunk float 4*m4 + j - d ->
    //   lo = rs4[PAD4+m4-dq-1], hi = rs4[PAD4+m4-dq]; word select literal per RR.
#define RRBODY(RR, SELX, SELY, SELZ, SELW)                                   \
    {                                                                        \
        float* od = obase + (size_t)RR * (HH * WW);                          \
        for (int dq = 0; dq < 12; ++dq, od += (size_t)4 * HH * WW) {         \
            const int d = 4 * dq + RR;                                       \
            int w4 = w40;                                                    \
            for (int m4 = tid; m4 < CH4; m4 += NT) {                         \
                const float4a a = ls4[m4];                                   \
                const int b4 = PAD4 + m4 - dq;                               \
                const float4a hi = rs4[b4];                                  \
                const float4a lo = (RR == 0) ? hi : rs4[b4 - 1];             \
                const int w = 4 * w4;                                        \
                float4a v;                                                   \
                v.x = (w     >= d) ? (a.x - (SELX)) : 1.0f;                  \
                v.y = (w + 1 >= d) ? (a.y - (SELY)) : 1.0f;                  \
                v.z = (w + 2 >= d) ? (a.z - (SELZ)) : 1.0f;                  \
                v.w = (w + 3 >= d) ? (a.w - (SELW)) : 1.0f;                  \
                *reinterpret_cast<float4a*>(od + 4 * m4) = v;                \
                w4 += W4STEP;                                                \
                if (w4 >= 78) w4 -= 78;                                      \
            }                                                                \
        }                                                                    \
    }

    RRBODY(0, hi.x, hi.y, hi.z, hi.w)
    RRBODY(1, lo.w, hi.x, hi.y, hi.z)
    RRBODY(2, lo.z, lo.w, hi.x, hi.y)
    RRBODY(3, lo.y, lo.z, lo.w, hi.x)
#undef RRBODY
}

extern "C" void kernel_launch(void* const* d_in, const int* in_sizes, int n_in,
                              void* d_out, int out_size, void* d_ws, size_t ws_size,
                              hipStream_t stream) {
    const float* l = (const float*)d_in[0];
    const float* r = (const float*)d_in[1];
    float* out = (float*)d_out;
    cost_volume_kernel<<<dim3(NBLOCKS), dim3(NT), 0, stream>>>(l, r, out);
}